// Round 5
// baseline (116.574 us; speedup 1.0000x reference)
//
#include <hip/hip_runtime.h>
#include <hip/hip_bf16.h>
#include <stdint.h>

// STFT as GEMM:  C[b,t,n] = sum_k frames[b,t,k] * basis[k, col(n)]
//   frames[b,t,k] = reflect_pad(x[b])[t*512 + k]   (pad 512 both sides)
//   col(n) = n+1 for n<512 (re half), n+2 for n>=512 (im half)
// Output: d_out = [re (8*4097*512) | im (8*4097*512)] fp32.
//
// v4: 256x256 8-phase schedule (T3+T4+T5 per the technique catalog):
//   512 thr = 8 waves (2Mx4N), wave tile 128x64, BK=64, LDS 128KB dbuf,
//   4 phases/K-tile {ds_read; stage half-tile; barrier; setprio; 16 MFMA;
//   setprio; barrier}, counted s_waitcnt vmcnt(2) once per K-tile (never 0),
//   staging leads 4-5 phases. Zero-conflict XOR chunk swizzle kept from v3
//   (pre-swizzled global source + linear LDS dest + swizzled frag read).

#define NX       2097152
#define NFRAMES  4097
#define NBATCH   8
#define KDIM     1024
#define BASIS_LD 1026
#define HALF_SZ  (NBATCH * NFRAMES * 512)

#define PADLEN   2163712   // 4224*512 + 1024, per batch (frame 4096 max)
#define XP_BYTES ((size_t)NBATCH * PADLEN * 2)
#define BIMG_OFF XP_BYTES
#define BIMG_BYTES ((size_t)4 * 16 * 16384 * 2)   // 2 MB
#define WS_NEEDED (BIMG_OFF + BIMG_BYTES)

#define MTILES3 17
#define NTILES3 4
#define GRID3   (NBATCH * MTILES3 * NTILES3)   // 544 = 8 * 68

typedef __attribute__((ext_vector_type(8))) short bf16x8;
typedef __attribute__((ext_vector_type(4))) float f32x4;

#define GLL16(src, dst) __builtin_amdgcn_global_load_lds( \
    (const __attribute__((address_space(1))) unsigned int*)(src), \
    (__attribute__((address_space(3))) unsigned int*)(dst), 16, 0, 0)

static __device__ __forceinline__ unsigned short f2bf(float f) {
    union { float f; uint32_t u; } v; v.f = f;
    uint32_t r = (v.u + 0x7FFFu + ((v.u >> 16) & 1u)) >> 16;  // RNE
    return (unsigned short)r;
}

// ---------------------------------------------------------------------------
// Kernel 0: x fp32 -> reflect-padded bf16 xp (per-batch PADLEN elems).
// ---------------------------------------------------------------------------
__global__ void convert_pad(const float* __restrict__ x,
                            unsigned short* __restrict__ xp) {
    const int per = PADLEN >> 2;
    int gid = blockIdx.x * 256 + threadIdx.x;
    int b   = gid / per;
    int i4  = (gid - b * per) << 2;
    const float* xb = x + (size_t)b * NX;
    int j = i4 - 512;
    unsigned short s0, s1, s2, s3;
    if (j >= 0 && j + 3 < NX) {
        float4 f = *(const float4*)(xb + j);
        s0 = f2bf(f.x); s1 = f2bf(f.y); s2 = f2bf(f.z); s3 = f2bf(f.w);
    } else {
        unsigned short ss[4];
        #pragma unroll
        for (int e = 0; e < 4; ++e) {
            int i = i4 + e;
            float v = 0.0f;
            if (i < NX + 1024) {
                int jj = i - 512;
                if (jj < 0) jj = -jj;
                else if (jj >= NX) jj = 2 * (NX - 1) - jj;
                v = xb[jj];
            }
            ss[e] = f2bf(v);
        }
        s0 = ss[0]; s1 = ss[1]; s2 = ss[2]; s3 = ss[3];
    }
    union { unsigned short s[4]; uint2 u; } p;
    p.s[0] = s0; p.s[1] = s1; p.s[2] = s2; p.s[3] = s3;
    *(uint2*)(xp + (size_t)b * PADLEN + i4) = p.u;
}

// ---------------------------------------------------------------------------
// Kernel 1: basis -> Bimg [nt2(4)][kt(16)][row(256)][slot(8)][8 bf16],
// slot = (k_local>>3) ^ (row&7): pre-swizzled for linear global_load_lds.
// ---------------------------------------------------------------------------
__global__ void basis_to_img(const float* __restrict__ basis,
                             unsigned short* __restrict__ Bimg) {
    __shared__ float L[64][65];
    const int kt  = blockIdx.x & 15;      // 64-wide k tile
    const int nt  = blockIdx.x >> 4;      // 64-wide n tile (0..15)
    const int tid = threadIdx.x;
    const int colbase = nt * 64 + (nt < 8 ? 1 : 2);   // re/im column select
    #pragma unroll
    for (int i = 0; i < 16; ++i) {
        int r = i * 4 + (tid >> 6);
        int c = tid & 63;
        L[r][c] = basis[(size_t)(kt * 64 + r) * BASIS_LD + colbase + c];
    }
    __syncthreads();
    #pragma unroll
    for (int i = 0; i < 16; ++i) {
        int nl = i * 4 + (tid >> 6);
        int kk = tid & 63;
        int n  = nt * 64 + nl;
        int nt2 = n >> 8, row = n & 255;
        int dslot = (kk >> 3) ^ (row & 7);
        size_t off = ((size_t)(nt2 * 16 + kt) * 256 + row) * 64 + dslot * 8 + (kk & 7);
        Bimg[off] = f2bf(L[kk][nl]);
    }
}

// ---------------------------------------------------------------------------
// Kernel 2: 256x256 8-phase bf16 MFMA GEMM.
// Half-tiles: 0=A rows 0-127, 1=A rows 128-255, 2=B rows 0-127, 3=B 128-255.
// Stage schedule: halves of tile t issued at phases (t-2,3),(t-1,0..2);
// vmcnt(2) at each tile boundary retires exactly tile t's 4 halves.
// ---------------------------------------------------------------------------
__device__ __forceinline__ void stage_half(
    int hid, int kt, int bufoff,
    const unsigned short* xpb, int t0, const unsigned short* bnt,
    unsigned short* Al, unsigned short* Bl, int tid)
{
    #pragma unroll
    for (int ld = 0; ld < 2; ++ld) {
        int q = ld * 512 + tid;
        if (hid < 2) {
            int row = q >> 3, d = q & 7;
            const unsigned short* src = xpb
                + (size_t)(t0 + hid * 128 + row) * 512
                + kt * 64 + ((d ^ (row & 7)) << 3);
            unsigned short* dst = Al + bufoff + hid * 8192
                + ((ld * 512 + (tid & 448)) << 3);
            GLL16(src, dst);
        } else {
            const unsigned short* src = bnt + kt * 16384 + (hid - 2) * 8192 + (q << 3);
            unsigned short* dst = Bl + bufoff + (hid - 2) * 8192
                + ((ld * 512 + (tid & 448)) << 3);
            GLL16(src, dst);
        }
    }
}

__global__ __launch_bounds__(512, 2) void stft_gemm3(
    const unsigned short* __restrict__ xp,
    const unsigned short* __restrict__ Bimg,
    float* __restrict__ out)
{
    __shared__ unsigned short Al[2 * 256 * 64];   // 64 KB, dbuf
    __shared__ unsigned short Bl[2 * 256 * 64];   // 64 KB, dbuf

    const int bid = blockIdx.x;
    const int wg  = (bid & 7) * (GRID3 / 8) + (bid >> 3);  // bijective XCD swizzle
    const int ntile = wg & 3;
    const int mtile = (wg >> 2) % MTILES3;
    const int batch = wg / (MTILES3 * NTILES3);

    const int tid  = threadIdx.x;
    const int lane = tid & 63;
    const int wid  = tid >> 6;
    const int wm   = wid >> 2;         // 0..1 -> 128-row band
    const int wn   = wid & 3;          // 0..3 -> 64-col band
    // tile 16 overlaps tile 15 (t0=3841): identical-value rewrites, no guards.
    const int t0   = (mtile < 16) ? mtile * 256 : 3841;
    const int n0   = ntile * 256;

    const unsigned short* __restrict__ xpb = xp + (size_t)batch * PADLEN;
    const unsigned short* __restrict__ bnt = Bimg + (size_t)ntile * 16 * 16384;

    const int l15 = lane & 15, l4 = lane >> 4;
    const int arow0 = wm * 128 + l15;
    const int brow0 = wn * 64 + l15;

    f32x4 acc[8][4];
    #pragma unroll
    for (int m = 0; m < 8; ++m)
        #pragma unroll
        for (int n = 0; n < 4; ++n)
            acc[m][n] = (f32x4)0.0f;

    bf16x8 a[4][2];   // current A m-group (4 m x 2 ks)
    bf16x8 b[4][2];   // all 4 B n-frags x 2 ks (held whole tile)

    // ---- prologue: tile0 all halves + tile1 A0; retire tile0 (vmcnt(2)) ----
    stage_half(0, 0, 0,     xpb, t0, bnt, Al, Bl, tid);
    stage_half(1, 0, 0,     xpb, t0, bnt, Al, Bl, tid);
    stage_half(2, 0, 0,     xpb, t0, bnt, Al, Bl, tid);
    stage_half(3, 0, 0,     xpb, t0, bnt, Al, Bl, tid);
    stage_half(0, 1, 16384, xpb, t0, bnt, Al, Bl, tid);
    asm volatile("s_waitcnt vmcnt(2)" ::: "memory");
    __builtin_amdgcn_s_barrier();

    #define LOAD_A(G) \
        _Pragma("unroll") \
        for (int j = 0; j < 4; ++j) { \
            _Pragma("unroll") \
            for (int ks = 0; ks < 2; ++ks) { \
                int row = arow0 + (G) * 64 + j * 16; \
                int slot = (ks * 4 + l4) ^ (row & 7); \
                a[j][ks] = *(const bf16x8*)(Al + cur + row * 64 + slot * 8); \
            } \
        }
    #define LOAD_B(NB) \
        _Pragma("unroll") \
        for (int n = 0; n < 2; ++n) { \
            _Pragma("unroll") \
            for (int ks = 0; ks < 2; ++ks) { \
                int row = brow0 + ((NB) * 2 + n) * 16; \
                int slot = (ks * 4 + l4) ^ (row & 7); \
                b[(NB) * 2 + n][ks] = *(const bf16x8*)(Bl + cur + row * 64 + slot * 8); \
            } \
        }
    #define MFMA_CLUSTER(G, NB) \
        __builtin_amdgcn_s_setprio(1); \
        _Pragma("unroll") \
        for (int j = 0; j < 4; ++j) { \
            _Pragma("unroll") \
            for (int n = 0; n < 2; ++n) { \
                _Pragma("unroll") \
                for (int ks = 0; ks < 2; ++ks) \
                    acc[(G) * 4 + j][(NB) * 2 + n] = \
                        __builtin_amdgcn_mfma_f32_16x16x32_bf16( \
                            a[j][ks], b[(NB) * 2 + n][ks], \
                            acc[(G) * 4 + j][(NB) * 2 + n], 0, 0, 0); \
            } \
        } \
        __builtin_amdgcn_s_setprio(0);

    for (int t = 0; t < 16; ++t) {
        const int cur = (t & 1) << 14;       // 16384-elem buffer offset
        const int nxt = cur ^ 16384;
        const int ktn  = (t + 1 < 16) ? t + 1 : 15;   // tail: redundant re-stage
        const int ktn2 = (t + 2 < 16) ? t + 2 : 15;   // (keeps vmcnt count uniform)

        // ---- phase 0: read A-group0 + B n0-1; stage A1(t+1) ----
        LOAD_A(0)
        LOAD_B(0)
        stage_half(1, ktn, nxt, xpb, t0, bnt, Al, Bl, tid);
        __builtin_amdgcn_s_barrier();
        MFMA_CLUSTER(0, 0)
        __builtin_amdgcn_s_barrier();

        // ---- phase 1: read B n2-3; stage B0(t+1) ----
        LOAD_B(1)
        stage_half(2, ktn, nxt, xpb, t0, bnt, Al, Bl, tid);
        __builtin_amdgcn_s_barrier();
        MFMA_CLUSTER(0, 1)
        __builtin_amdgcn_s_barrier();

        // ---- phase 2: read A-group1; stage B1(t+1) ----
        LOAD_A(1)
        stage_half(3, ktn, nxt, xpb, t0, bnt, Al, Bl, tid);
        __builtin_amdgcn_s_barrier();
        MFMA_CLUSTER(1, 1)
        __builtin_amdgcn_s_barrier();

        // ---- phase 3: stage A0(t+2) into cur (region dead after phase 0);
        //      boundary: counted vmcnt(2) retires tile t+1's 4 halves. ----
        stage_half(0, ktn2, cur, xpb, t0, bnt, Al, Bl, tid);
        __builtin_amdgcn_s_barrier();
        MFMA_CLUSTER(1, 0)
        asm volatile("s_waitcnt vmcnt(2)" ::: "memory");
        __builtin_amdgcn_s_barrier();
    }
    #undef LOAD_A
    #undef LOAD_B
    #undef MFMA_CLUSTER

    // ---- epilogue: C/D layout (m89): col = lane&15, row = (lane>>4)*4 + reg
    #pragma unroll
    for (int m = 0; m < 8; ++m) {
        const int trow0 = t0 + wm * 128 + m * 16 + (l4 << 2);
        #pragma unroll
        for (int r = 0; r < 4; ++r) {
            const int t = trow0 + r;
            const size_t rowbase = (size_t)batch * (NFRAMES * 512) + (size_t)t * 512;
            #pragma unroll
            for (int n = 0; n < 4; ++n) {
                const int gc = n0 + wn * 64 + n * 16 + l15;
                const size_t o = (size_t)(gc >> 9) * HALF_SZ + rowbase + (gc & 511);
                out[o] = acc[m][n][r];
            }
        }
    }
}

// ===========================================================================
// Fallback path (round-2 kernels, proven pass) — used only if ws too small.
// ===========================================================================
#define BM 128
#define BN 128
#define BK 64
#define LDPAD 72
#define MTILES 33
#define NTILES 8
#define GRID   (NBATCH * MTILES * NTILES)

__global__ void basis_transpose_fb(const float* __restrict__ basis,
                                   unsigned short* __restrict__ Bt) {
    __shared__ float L[64][65];
    const int kt  = blockIdx.x & 15;
    const int nt  = blockIdx.x >> 4;
    const int tid = threadIdx.x;
    const int colbase = nt * 64 + (nt < 8 ? 1 : 2);
    #pragma unroll
    for (int i = 0; i < 16; ++i) {
        int r = i * 4 + (tid >> 6);
        int c = tid & 63;
        L[r][c] = basis[(size_t)(kt * 64 + r) * BASIS_LD + colbase + c];
    }
    __syncthreads();
    #pragma unroll
    for (int i = 0; i < 16; ++i) {
        int n = i * 4 + (tid >> 6);
        int k = tid & 63;
        Bt[(size_t)(nt * 64 + n) * 1024 + kt * 64 + k] = f2bf(L[k][n]);
    }
}

__global__ __launch_bounds__(256, 2) void stft_gemm_fb(
    const float* __restrict__ x,
    const unsigned short* __restrict__ Bt,
    float* __restrict__ out)
{
    __shared__ unsigned short Al[BM * LDPAD];
    __shared__ unsigned short Bl[BN * LDPAD];
    const int bid = blockIdx.x;
    const int wg  = (bid & 7) * (GRID / 8) + (bid >> 3);
    const int ntile = wg & 7;
    const int mtile = (wg >> 3) % MTILES;
    const int batch = wg / (MTILES * NTILES);
    const int tid  = threadIdx.x;
    const int lane = tid & 63;
    const int wid  = tid >> 6;
    const int wr   = wid >> 1;
    const int wc   = wid & 1;
    const int t0 = mtile * BM;
    const int n0 = ntile * BN;
    const float* __restrict__ xb = x + (size_t)batch * NX;

    f32x4 acc[4][4];
    #pragma unroll
    for (int m = 0; m < 4; ++m)
        #pragma unroll
        for (int n = 0; n < 4; ++n)
            acc[m][n] = (f32x4)0.0f;

    for (int k0 = 0; k0 < KDIM; k0 += BK) {
        #pragma unroll
        for (int it = 0; it < 8; ++it) {
            int idx = it * 256 + tid;
            int row = idx >> 4;
            int c4  = idx & 15;
            int t   = t0 + row;
            float v0, v1, v2, v3;
            int j = t * 512 + k0 + c4 * 4 - 512;
            if (t <= 4096) {
                if (j >= 0 && j + 3 < NX) {
                    const float4 f = *(const float4*)(xb + j);
                    v0 = f.x; v1 = f.y; v2 = f.z; v3 = f.w;
                } else {
                    float vv[4];
                    #pragma unroll
                    for (int e = 0; e < 4; ++e) {
                        int jj = j + e;
                        if (jj < 0) jj = -jj;
                        else if (jj >= NX) jj = 2 * (NX - 1) - jj;
                        vv[e] = xb[jj];
                    }
                    v0 = vv[0]; v1 = vv[1]; v2 = vv[2]; v3 = vv[3];
                }
            } else {
                v0 = v1 = v2 = v3 = 0.0f;
            }
            union { unsigned short s[4]; uint32_t u[2]; } p;
            p.s[0] = f2bf(v0); p.s[1] = f2bf(v1);
            p.s[2] = f2bf(v2); p.s[3] = f2bf(v3);
            *(uint32_t*)(Al + row * LDPAD + c4 * 4)     = p.u[0];
            *(uint32_t*)(Al + row * LDPAD + c4 * 4 + 2) = p.u[1];
        }
        #pragma unroll
        for (int it = 0; it < 4; ++it) {
            int idx = it * 256 + tid;
            int n  = idx >> 3;
            int kc = idx & 7;
            uint4 v = *(const uint4*)(Bt + (size_t)(n0 + n) * 1024 + k0 + kc * 8);
            *(uint4*)(Bl + n * LDPAD + kc * 8) = v;
        }
        __syncthreads();
        #pragma unroll
        for (int ks = 0; ks < 2; ++ks) {
            bf16x8 af[4], bfr[4];
            #pragma unroll
            for (int m = 0; m < 4; ++m)
                af[m] = *(const bf16x8*)(Al + (wr * 64 + m * 16 + (lane & 15)) * LDPAD
                                            + ks * 32 + (lane >> 4) * 8);
            #pragma unroll
            for (int n = 0; n < 4; ++n)
                bfr[n] = *(const bf16x8*)(Bl + (wc * 64 + n * 16 + (lane & 15)) * LDPAD
                                             + ks * 32 + (lane >> 4) * 8);
            #pragma unroll
            for (int m = 0; m < 4; ++m)
                #pragma unroll
                for (int n = 0; n < 4; ++n)
                    acc[m][n] = __builtin_amdgcn_mfma_f32_16x16x32_bf16(
                        af[m], bfr[n], acc[m][n], 0, 0, 0);
        }
        __syncthreads();
    }
    const int colb = n0 + wc * 64 + (lane & 15);
    #pragma unroll
    for (int m = 0; m < 4; ++m) {
        const int trow0 = t0 + wr * 64 + m * 16 + ((lane >> 4) << 2);
        #pragma unroll
        for (int r = 0; r < 4; ++r) {
            const int t = trow0 + r;
            if (t > 4096) continue;
            const size_t rowbase = (size_t)batch * (NFRAMES * 512) + (size_t)t * 512;
            #pragma unroll
            for (int n = 0; n < 4; ++n) {
                const int gc = colb + n * 16;
                const size_t o = (size_t)(gc >> 9) * HALF_SZ + rowbase + (gc & 511);
                out[o] = acc[m][n][r];
            }
        }
    }
}

extern "C" void kernel_launch(void* const* d_in, const int* in_sizes, int n_in,
                              void* d_out, int out_size, void* d_ws, size_t ws_size,
                              hipStream_t stream) {
    const float* x     = (const float*)d_in[0];
    const float* basis = (const float*)d_in[1];
    float* out = (float*)d_out;

    if (ws_size >= WS_NEEDED) {
        unsigned short* xp   = (unsigned short*)d_ws;
        unsigned short* Bimg = (unsigned short*)((char*)d_ws + BIMG_OFF);
        convert_pad<<<(NBATCH * (PADLEN >> 2)) / 256, 256, 0, stream>>>(x, xp);
        basis_to_img<<<256, 256, 0, stream>>>(basis, Bimg);
        stft_gemm3<<<GRID3, 512, 0, stream>>>(xp, Bimg, out);
    } else {
        unsigned short* Bt = (unsigned short*)d_ws;
        basis_transpose_fb<<<256, 256, 0, stream>>>(basis, Bt);
        stft_gemm_fb<<<GRID, 256, 0, stream>>>(x, Bt, out);
    }
}

// Round 7
// 103.937 us; speedup vs baseline: 1.1216x; 1.1216x over previous
//
#include <hip/hip_runtime.h>
#include <hip/hip_bf16.h>
#include <stdint.h>

// STFT as GEMM:  C[b,t,n] = sum_k frames[b,t,k] * basis[k, col(n)]
//   frames[b,t,k] = reflect_pad(x[b])[t*512 + k]   (pad 512 both sides)
//   col(n) = n+1 for n<512 (re half), n+2 for n>=512 (im half)
// Output: d_out = [re (8*4097*512) | im (8*4097*512)] fp32.
//
// v6 = v3 (last-known-good: 78us GEMM, 0 bank conflicts) + one structural
// change, no inline asm:
//   * B operand never touches LDS: basis pre-packed in MFMA-fragment order
//     (Bfrag), loaded per K-tile with plain bf16x8 global loads (compiler
//     owns waitcnt correctness). Halves LDS reads and staged bytes/barrier.
//   * A LDS double-buffered (2x16KB): stage(t+1) issued at top of iter t,
//     single __syncthreads()/K-tile; drain covers loads issued one full
//     compute phase earlier.

#define NX       2097152
#define NFRAMES  4097
#define NBATCH   8
#define KDIM     1024
#define BASIS_LD 1026
#define HALF_SZ  (NBATCH * NFRAMES * 512)

#define PADLEN   2163712   // 4224*512 + 1024, per batch
#define XP_BYTES ((size_t)NBATCH * PADLEN * 2)
#define BFRAG_OFF XP_BYTES
#define BFRAG_BYTES ((size_t)64 * 32 * 64 * 8 * 2)   // 2 MB
#define WS_NEEDED (BFRAG_OFF + BFRAG_BYTES)

#define MTILES 33  // ceil(4097/128)
#define NTILES 8   // 1024/128
#define GRID   (NBATCH * MTILES * NTILES)  // 2112 = 8 * 264

typedef __attribute__((ext_vector_type(8))) short bf16x8;
typedef __attribute__((ext_vector_type(4))) float f32x4;

#define GLL16(src, dst) __builtin_amdgcn_global_load_lds( \
    (const __attribute__((address_space(1))) unsigned int*)(src), \
    (__attribute__((address_space(3))) unsigned int*)(dst), 16, 0, 0)

static __device__ __forceinline__ unsigned short f2bf(float f) {
    union { float f; uint32_t u; } v; v.f = f;
    uint32_t r = (v.u + 0x7FFFu + ((v.u >> 16) & 1u)) >> 16;  // RNE
    return (unsigned short)r;
}

// ---------------------------------------------------------------------------
// Kernel 0: x fp32 -> reflect-padded bf16 xp (per-batch PADLEN elems).
// ---------------------------------------------------------------------------
__global__ void convert_pad(const float* __restrict__ x,
                            unsigned short* __restrict__ xp) {
    const int per = PADLEN >> 2;
    int gid = blockIdx.x * 256 + threadIdx.x;
    int b   = gid / per;
    int i4  = (gid - b * per) << 2;
    const float* xb = x + (size_t)b * NX;
    int j = i4 - 512;
    unsigned short s0, s1, s2, s3;
    if (j >= 0 && j + 3 < NX) {
        float4 f = *(const float4*)(xb + j);
        s0 = f2bf(f.x); s1 = f2bf(f.y); s2 = f2bf(f.z); s3 = f2bf(f.w);
    } else {
        unsigned short ss[4];
        #pragma unroll
        for (int e = 0; e < 4; ++e) {
            int i = i4 + e;
            float v = 0.0f;
            if (i < NX + 1024) {
                int jj = i - 512;
                if (jj < 0) jj = -jj;
                else if (jj >= NX) jj = 2 * (NX - 1) - jj;
                v = xb[jj];
            }
            ss[e] = f2bf(v);
        }
        s0 = ss[0]; s1 = ss[1]; s2 = ss[2]; s3 = ss[3];
    }
    union { unsigned short s[4]; uint2 u; } p;
    p.s[0] = s0; p.s[1] = s1; p.s[2] = s2; p.s[3] = s3;
    *(uint2*)(xp + (size_t)b * PADLEN + i4) = p.u;
}

// ---------------------------------------------------------------------------
// Kernel 1: basis -> Bfrag in MFMA-fragment order.
//   Bfrag elem offset = ((fn*32 + ks32)*64 + lane)*8 + j
//     holds bf16(basis[ks32*32 + (lane>>4)*8 + j][col(fn*16 + (lane&15))])
// One (fn,ks32) fragment = 64 lanes x 16B contiguous -> coalesced frag loads.
// ---------------------------------------------------------------------------
__global__ void basis_to_frag(const float* __restrict__ basis,
                              unsigned short* __restrict__ Bfrag) {
    int idx  = blockIdx.x * 256 + threadIdx.x;   // 0..131071
    int lane = idx & 63;
    int ks32 = (idx >> 6) & 31;
    int fn   = idx >> 11;                        // 0..63
    int n    = fn * 16 + (lane & 15);
    int kb   = ks32 * 32 + (lane >> 4) * 8;
    int col  = n + 1 + (n >= 512);
    #pragma unroll
    for (int j = 0; j < 8; ++j)
        Bfrag[(size_t)idx * 8 + j] = f2bf(basis[(size_t)(kb + j) * BASIS_LD + col]);
}

// ---------------------------------------------------------------------------
// Kernel 2: 128x128 bf16 MFMA GEMM. 4 waves (2x2), 64x64 quadrant/wave,
// BK=64. A: dbuf LDS via GLL16 + proven XOR chunk swizzle. B: registers only.
// ---------------------------------------------------------------------------
__global__ __launch_bounds__(256, 3) void stft_gemm5(
    const unsigned short* __restrict__ xp,
    const unsigned short* __restrict__ Bfrag,
    float* __restrict__ out)
{
    __shared__ unsigned short Al[2][128 * 64];   // 2 x 16 KB, A double-buffer

    const int bid = blockIdx.x;
    const int wg  = (bid & 7) * (GRID / 8) + (bid >> 3);   // bijective XCD swizzle
    const int ntile = wg & 7;
    const int mtile = (wg >> 3) % MTILES;
    const int batch = wg / (MTILES * NTILES);

    const int tid  = threadIdx.x;
    const int lane = tid & 63;
    const int wr   = tid >> 7;         // wave row 0..1
    const int wc   = (tid >> 6) & 1;   // wave col 0..1
    const int t0   = mtile * 128;
    const int n0   = ntile * 128;

    const unsigned short* __restrict__ xpb = xp + (size_t)batch * PADLEN;
    const int l15 = lane & 15, l4 = lane >> 4;

    // this wave's B fragment base: fn0 = (n0 + wc*64)/16
    const unsigned short* __restrict__ bfr =
        Bfrag + (size_t)(ntile * 8 + wc * 4) * 16384 + lane * 8;

    f32x4 acc[4][4];
    #pragma unroll
    for (int m = 0; m < 4; ++m)
        #pragma unroll
        for (int n = 0; n < 4; ++n)
            acc[m][n] = (f32x4)0.0f;

    // ---- A staging: 1024 x 16B chunks, linear LDS dest, swizzled source ----
    #define STAGE_A(KT, BUF) { \
        _Pragma("unroll") \
        for (int i = 0; i < 4; ++i) { \
            int q   = i * 256 + tid; \
            int row = q >> 3, d = q & 7; \
            const unsigned short* src = xpb \
                + (size_t)(t0 + row) * 512 + (KT) * 64 + ((d ^ (row & 7)) << 3); \
            unsigned short* dst = &Al[BUF][0] + ((i * 256 + (tid & 192)) << 3); \
            GLL16(src, dst); \
        } }

    // ---- prologue: tile 0 -> buf 0 ----
    STAGE_A(0, 0)
    __syncthreads();   // compiler drains vmcnt(0): buf0 ready

    for (int kt = 0; kt < 16; ++kt) {
        const int cb = kt & 1;
        if (kt < 15) STAGE_A(kt + 1, cb ^ 1)   // overlaps with this tile's compute

        const unsigned short* bp = bfr + (size_t)kt * 1024;   // ks32 = 2*kt
        #pragma unroll
        for (int s = 0; s < 2; ++s) {
            bf16x8 bv[4], av[4];
            #pragma unroll
            for (int j = 0; j < 4; ++j)
                bv[j] = *(const bf16x8*)(bp + (size_t)j * 16384 + s * 512);
            #pragma unroll
            for (int m = 0; m < 4; ++m) {
                int row  = wr * 64 + m * 16 + l15;
                int slot = (s * 4 + l4) ^ (row & 7);
                av[m] = *(const bf16x8*)(&Al[cb][row * 64 + slot * 8]);
            }
            #pragma unroll
            for (int m = 0; m < 4; ++m)
                #pragma unroll
                for (int n = 0; n < 4; ++n)
                    acc[m][n] = __builtin_amdgcn_mfma_f32_16x16x32_bf16(
                        av[m], bv[n], acc[m][n], 0, 0, 0);
        }
        __syncthreads();   // drains stage(kt+1); buf cb^1 ready for next iter
    }
    #undef STAGE_A

    // ---- epilogue: C/D layout (m89): col = lane&15, row = (lane>>4)*4 + reg
    const int colb = n0 + wc * 64 + l15;
    #pragma unroll
    for (int m = 0; m < 4; ++m) {
        const int trow0 = t0 + wr * 64 + m * 16 + (l4 << 2);
        #pragma unroll
        for (int r = 0; r < 4; ++r) {
            const int t = trow0 + r;
            if (t > 4096) continue;   // tail tile: only valid frames
            const size_t rowbase = (size_t)batch * (NFRAMES * 512) + (size_t)t * 512;
            #pragma unroll
            for (int n = 0; n < 4; ++n) {
                const int gc = colb + n * 16;
                const size_t o = (size_t)(gc >> 9) * HALF_SZ + rowbase + (gc & 511);
                out[o] = acc[m][n][r];
            }
        }
    }
}

// ===========================================================================
// Fallback path (round-2 kernels, proven pass) — used only if ws too small.
// ===========================================================================
#define BM 128
#define BN 128
#define BK 64
#define LDPAD 72

__global__ void basis_transpose_fb(const float* __restrict__ basis,
                                   unsigned short* __restrict__ Bt) {
    __shared__ float L[64][65];
    const int kt  = blockIdx.x & 15;
    const int nt  = blockIdx.x >> 4;
    const int tid = threadIdx.x;
    const int colbase = nt * 64 + (nt < 8 ? 1 : 2);
    #pragma unroll
    for (int i = 0; i < 16; ++i) {
        int r = i * 4 + (tid >> 6);
        int c = tid & 63;
        L[r][c] = basis[(size_t)(kt * 64 + r) * BASIS_LD + colbase + c];
    }
    __syncthreads();
    #pragma unroll
    for (int i = 0; i < 16; ++i) {
        int n = i * 4 + (tid >> 6);
        int k = tid & 63;
        Bt[(size_t)(nt * 64 + n) * 1024 + kt * 64 + k] = f2bf(L[k][n]);
    }
}

__global__ __launch_bounds__(256, 2) void stft_gemm_fb(
    const float* __restrict__ x,
    const unsigned short* __restrict__ Bt,
    float* __restrict__ out)
{
    __shared__ unsigned short Al[BM * LDPAD];
    __shared__ unsigned short Bl[BN * LDPAD];
    const int bid = blockIdx.x;
    const int wg  = (bid & 7) * (GRID / 8) + (bid >> 3);
    const int ntile = wg & 7;
    const int mtile = (wg >> 3) % MTILES;
    const int batch = wg / (MTILES * NTILES);
    const int tid  = threadIdx.x;
    const int lane = tid & 63;
    const int wid  = tid >> 6;
    const int wr   = wid >> 1;
    const int wc   = wid & 1;
    const int t0 = mtile * BM;
    const int n0 = ntile * BN;
    const float* __restrict__ xb = x + (size_t)batch * NX;

    f32x4 acc[4][4];
    #pragma unroll
    for (int m = 0; m < 4; ++m)
        #pragma unroll
        for (int n = 0; n < 4; ++n)
            acc[m][n] = (f32x4)0.0f;

    for (int k0 = 0; k0 < KDIM; k0 += BK) {
        #pragma unroll
        for (int it = 0; it < 8; ++it) {
            int idx = it * 256 + tid;
            int row = idx >> 4;
            int c4  = idx & 15;
            int t   = t0 + row;
            float v0, v1, v2, v3;
            int j = t * 512 + k0 + c4 * 4 - 512;
            if (t <= 4096) {
                if (j >= 0 && j + 3 < NX) {
                    const float4 f = *(const float4*)(xb + j);
                    v0 = f.x; v1 = f.y; v2 = f.z; v3 = f.w;
                } else {
                    float vv[4];
                    #pragma unroll
                    for (int e = 0; e < 4; ++e) {
                        int jj = j + e;
                        if (jj < 0) jj = -jj;
                        else if (jj >= NX) jj = 2 * (NX - 1) - jj;
                        vv[e] = xb[jj];
                    }
                    v0 = vv[0]; v1 = vv[1]; v2 = vv[2]; v3 = vv[3];
                }
            } else {
                v0 = v1 = v2 = v3 = 0.0f;
            }
            union { unsigned short s[4]; uint32_t u[2]; } p;
            p.s[0] = f2bf(v0); p.s[1] = f2bf(v1);
            p.s[2] = f2bf(v2); p.s[3] = f2bf(v3);
            *(uint32_t*)(Al + row * LDPAD + c4 * 4)     = p.u[0];
            *(uint32_t*)(Al + row * LDPAD + c4 * 4 + 2) = p.u[1];
        }
        #pragma unroll
        for (int it = 0; it < 4; ++it) {
            int idx = it * 256 + tid;
            int n  = idx >> 3;
            int kc = idx & 7;
            uint4 v = *(const uint4*)(Bt + (size_t)(n0 + n) * 1024 + k0 + kc * 8);
            *(uint4*)(Bl + n * LDPAD + kc * 8) = v;
        }
        __syncthreads();
        #pragma unroll
        for (int ks = 0; ks < 2; ++ks) {
            bf16x8 af[4], bfr[4];
            #pragma unroll
            for (int m = 0; m < 4; ++m)
                af[m] = *(const bf16x8*)(Al + (wr * 64 + m * 16 + (lane & 15)) * LDPAD
                                            + ks * 32 + (lane >> 4) * 8);
            #pragma unroll
            for (int n = 0; n < 4; ++n)
                bfr[n] = *(const bf16x8*)(Bl + (wc * 64 + n * 16 + (lane & 15)) * LDPAD
                                             + ks * 32 + (lane >> 4) * 8);
            #pragma unroll
            for (int m = 0; m < 4; ++m)
                #pragma unroll
                for (int n = 0; n < 4; ++n)
                    acc[m][n] = __builtin_amdgcn_mfma_f32_16x16x32_bf16(
                        af[m], bfr[n], acc[m][n], 0, 0, 0);
        }
        __syncthreads();
    }
    const int colb = n0 + wc * 64 + (lane & 15);
    #pragma unroll
    for (int m = 0; m < 4; ++m) {
        const int trow0 = t0 + wr * 64 + m * 16 + ((lane >> 4) << 2);
        #pragma unroll
        for (int r = 0; r < 4; ++r) {
            const int t = trow0 + r;
            if (t > 4096) continue;
            const size_t rowbase = (size_t)batch * (NFRAMES * 512) + (size_t)t * 512;
            #pragma unroll
            for (int n = 0; n < 4; ++n) {
                const int gc = colb + n * 16;
                const size_t o = (size_t)(gc >> 9) * HALF_SZ + rowbase + (gc & 511);
                out[o] = acc[m][n][r];
            }
        }
    }
}

extern "C" void kernel_launch(void* const* d_in, const int* in_sizes, int n_in,
                              void* d_out, int out_size, void* d_ws, size_t ws_size,
                              hipStream_t stream) {
    const float* x     = (const float*)d_in[0];
    const float* basis = (const float*)d_in[1];
    float* out = (float*)d_out;

    if (ws_size >= WS_NEEDED) {
        unsigned short* xp    = (unsigned short*)d_ws;
        unsigned short* Bfrag = (unsigned short*)((char*)d_ws + BFRAG_OFF);
        convert_pad<<<(NBATCH * (PADLEN >> 2)) / 256, 256, 0, stream>>>(x, xp);
        basis_to_frag<<<512, 256, 0, stream>>>(basis, Bfrag);
        stft_gemm5<<<GRID, 256, 0, stream>>>(xp, Bfrag, out);
    } else {
        unsigned short* Bt = (unsigned short*)d_ws;
        basis_transpose_fb<<<256, 256, 0, stream>>>(basis, Bt);
        stft_gemm_fb<<<GRID, 256, 0, stream>>>(x, Bt, out);
    }
}

// Round 8
// 102.976 us; speedup vs baseline: 1.1320x; 1.0093x over previous
//
#include <hip/hip_runtime.h>
#include <hip/hip_bf16.h>
#include <stdint.h>

// STFT as GEMM:  C[b,t,n] = sum_k frames[b,t,k] * basis[k, col(n)]
//   frames[b,t,k] = reflect_pad(x[b])[t*512 + k]   (pad 512 both sides)
//   col(n) = n+1 for n<512 (re half), n+2 for n>=512 (im half)
// Output: d_out = [re (8*4097*512) | im (8*4097*512)] fp32.
//
// v7 = v6 with the vmcnt-ordering fix:
//   In-order vmcnt retirement means anything issued BEFORE the bv loads
//   retires first. v6 issued STAGE_A(t+1) before bv(t) -> consuming bv
//   waited for next-tile staging (serialized the pipeline). v7 issues all
//   8 bv loads at iteration top (pinned with sched_barrier(0)), then
//   STAGE_A(t+1): bv waits leave the 4 stage GLL16s in flight, and staging
//   has the whole compute phase to complete before the barrier drain.

#define NX       2097152
#define NFRAMES  4097
#define NBATCH   8
#define KDIM     1024
#define BASIS_LD 1026
#define HALF_SZ  (NBATCH * NFRAMES * 512)

#define PADLEN   2163712   // 4224*512 + 1024, per batch
#define XP_BYTES ((size_t)NBATCH * PADLEN * 2)
#define BFRAG_OFF XP_BYTES
#define BFRAG_BYTES ((size_t)64 * 32 * 64 * 8 * 2)   // 2 MB
#define WS_NEEDED (BFRAG_OFF + BFRAG_BYTES)

#define MTILES 33  // ceil(4097/128)
#define NTILES 8   // 1024/128
#define GRID   (NBATCH * MTILES * NTILES)  // 2112 = 8 * 264

typedef __attribute__((ext_vector_type(8))) short bf16x8;
typedef __attribute__((ext_vector_type(4))) float f32x4;

#define GLL16(src, dst) __builtin_amdgcn_global_load_lds( \
    (const __attribute__((address_space(1))) unsigned int*)(src), \
    (__attribute__((address_space(3))) unsigned int*)(dst), 16, 0, 0)

static __device__ __forceinline__ unsigned short f2bf(float f) {
    union { float f; uint32_t u; } v; v.f = f;
    uint32_t r = (v.u + 0x7FFFu + ((v.u >> 16) & 1u)) >> 16;  // RNE
    return (unsigned short)r;
}

// ---------------------------------------------------------------------------
// Kernel 0: x fp32 -> reflect-padded bf16 xp (per-batch PADLEN elems).
// ---------------------------------------------------------------------------
__global__ void convert_pad(const float* __restrict__ x,
                            unsigned short* __restrict__ xp) {
    const int per = PADLEN >> 2;
    int gid = blockIdx.x * 256 + threadIdx.x;
    int b   = gid / per;
    int i4  = (gid - b * per) << 2;
    const float* xb = x + (size_t)b * NX;
    int j = i4 - 512;
    unsigned short s0, s1, s2, s3;
    if (j >= 0 && j + 3 < NX) {
        float4 f = *(const float4*)(xb + j);
        s0 = f2bf(f.x); s1 = f2bf(f.y); s2 = f2bf(f.z); s3 = f2bf(f.w);
    } else {
        unsigned short ss[4];
        #pragma unroll
        for (int e = 0; e < 4; ++e) {
            int i = i4 + e;
            float v = 0.0f;
            if (i < NX + 1024) {
                int jj = i - 512;
                if (jj < 0) jj = -jj;
                else if (jj >= NX) jj = 2 * (NX - 1) - jj;
                v = xb[jj];
            }
            ss[e] = f2bf(v);
        }
        s0 = ss[0]; s1 = ss[1]; s2 = ss[2]; s3 = ss[3];
    }
    union { unsigned short s[4]; uint2 u; } p;
    p.s[0] = s0; p.s[1] = s1; p.s[2] = s2; p.s[3] = s3;
    *(uint2*)(xp + (size_t)b * PADLEN + i4) = p.u;
}

// ---------------------------------------------------------------------------
// Kernel 1: basis -> Bfrag in MFMA-fragment order.
//   Bfrag elem offset = ((fn*32 + ks32)*64 + lane)*8 + j
//     holds bf16(basis[ks32*32 + (lane>>4)*8 + j][col(fn*16 + (lane&15))])
// One (fn,ks32) fragment = 64 lanes x 16B contiguous -> coalesced frag loads.
// ---------------------------------------------------------------------------
__global__ void basis_to_frag(const float* __restrict__ basis,
                              unsigned short* __restrict__ Bfrag) {
    int idx  = blockIdx.x * 256 + threadIdx.x;   // 0..131071
    int lane = idx & 63;
    int ks32 = (idx >> 6) & 31;
    int fn   = idx >> 11;                        // 0..63
    int n    = fn * 16 + (lane & 15);
    int kb   = ks32 * 32 + (lane >> 4) * 8;
    int col  = n + 1 + (n >= 512);
    #pragma unroll
    for (int j = 0; j < 8; ++j)
        Bfrag[(size_t)idx * 8 + j] = f2bf(basis[(size_t)(kb + j) * BASIS_LD + col]);
}

// ---------------------------------------------------------------------------
// Kernel 2: 128x128 bf16 MFMA GEMM. 4 waves (2x2), 64x64 quadrant/wave,
// BK=64. A: dbuf LDS via GLL16 + proven XOR chunk swizzle. B: registers only.
// Per-iteration order (vmcnt-critical): bv loads -> sched_barrier ->
// STAGE_A(t+1) -> ds_read+MFMA -> __syncthreads.
// ---------------------------------------------------------------------------
__global__ __launch_bounds__(256, 3) void stft_gemm6(
    const unsigned short* __restrict__ xp,
    const unsigned short* __restrict__ Bfrag,
    float* __restrict__ out)
{
    __shared__ unsigned short Al[2][128 * 64];   // 2 x 16 KB, A double-buffer

    const int bid = blockIdx.x;
    const int wg  = (bid & 7) * (GRID / 8) + (bid >> 3);   // bijective XCD swizzle
    const int ntile = wg & 7;
    const int mtile = (wg >> 3) % MTILES;
    const int batch = wg / (MTILES * NTILES);

    const int tid  = threadIdx.x;
    const int lane = tid & 63;
    const int wr   = tid >> 7;         // wave row 0..1
    const int wc   = (tid >> 6) & 1;   // wave col 0..1
    const int t0   = mtile * 128;
    const int n0   = ntile * 128;

    const unsigned short* __restrict__ xpb = xp + (size_t)batch * PADLEN;
    const int l15 = lane & 15, l4 = lane >> 4;

    // this wave's B fragment base: fn0 = (n0 + wc*64)/16
    const unsigned short* __restrict__ bfr =
        Bfrag + (size_t)(ntile * 8 + wc * 4) * 16384 + lane * 8;

    f32x4 acc[4][4];
    #pragma unroll
    for (int m = 0; m < 4; ++m)
        #pragma unroll
        for (int n = 0; n < 4; ++n)
            acc[m][n] = (f32x4)0.0f;

    // ---- A staging: 1024 x 16B chunks, linear LDS dest, swizzled source ----
    #define STAGE_A(KT, BUF) { \
        _Pragma("unroll") \
        for (int i = 0; i < 4; ++i) { \
            int q   = i * 256 + tid; \
            int row = q >> 3, d = q & 7; \
            const unsigned short* src = xpb \
                + (size_t)(t0 + row) * 512 + (KT) * 64 + ((d ^ (row & 7)) << 3); \
            unsigned short* dst = &Al[BUF][0] + ((i * 256 + (tid & 192)) << 3); \
            GLL16(src, dst); \
        } }

    // ---- prologue: tile 0 -> buf 0 ----
    STAGE_A(0, 0)
    __syncthreads();   // compiler drains vmcnt(0): buf0 ready

    for (int kt = 0; kt < 16; ++kt) {
        const int cb = kt & 1;

        // (1) B fragment loads for THIS tile — issued first so their vmcnt
        //     retirement does not depend on next-tile staging.
        const unsigned short* bp = bfr + (size_t)kt * 1024;   // ks32 = 2*kt
        bf16x8 bv[2][4];
        #pragma unroll
        for (int s = 0; s < 2; ++s)
            #pragma unroll
            for (int j = 0; j < 4; ++j)
                bv[s][j] = *(const bf16x8*)(bp + (size_t)j * 16384 + s * 512);
        __builtin_amdgcn_sched_barrier(0);   // pin: bv issue before GLL16s

        // (2) stage next tile into the other buffer (latency hidden by compute)
        if (kt < 15) STAGE_A(kt + 1, cb ^ 1)

        // (3) compute: ds_read A frags + MFMA (bv wait leaves GLL16s in flight)
        #pragma unroll
        for (int s = 0; s < 2; ++s) {
            bf16x8 av[4];
            #pragma unroll
            for (int m = 0; m < 4; ++m) {
                int row  = wr * 64 + m * 16 + l15;
                int slot = (s * 4 + l4) ^ (row & 7);
                av[m] = *(const bf16x8*)(&Al[cb][row * 64 + slot * 8]);
            }
            #pragma unroll
            for (int m = 0; m < 4; ++m)
                #pragma unroll
                for (int n = 0; n < 4; ++n)
                    acc[m][n] = __builtin_amdgcn_mfma_f32_16x16x32_bf16(
                        av[m], bv[s][n], acc[m][n], 0, 0, 0);
        }
        __syncthreads();   // drains stage(kt+1); buf cb^1 ready for next iter
    }
    #undef STAGE_A

    // ---- epilogue: C/D layout (m89): col = lane&15, row = (lane>>4)*4 + reg
    const int colb = n0 + wc * 64 + l15;
    #pragma unroll
    for (int m = 0; m < 4; ++m) {
        const int trow0 = t0 + wr * 64 + m * 16 + (l4 << 2);
        #pragma unroll
        for (int r = 0; r < 4; ++r) {
            const int t = trow0 + r;
            if (t > 4096) continue;   // tail tile: only valid frames
            const size_t rowbase = (size_t)batch * (NFRAMES * 512) + (size_t)t * 512;
            #pragma unroll
            for (int n = 0; n < 4; ++n) {
                const int gc = colb + n * 16;
                const size_t o = (size_t)(gc >> 9) * HALF_SZ + rowbase + (gc & 511);
                out[o] = acc[m][n][r];
            }
        }
    }
}

// ===========================================================================
// Fallback path (round-2 kernels, proven pass) — used only if ws too small.
// ===========================================================================
#define BM 128
#define BN 128
#define BK 64
#define LDPAD 72

__global__ void basis_transpose_fb(const float* __restrict__ basis,
                                   unsigned short* __restrict__ Bt) {
    __shared__ float L[64][65];
    const int kt  = blockIdx.x & 15;
    const int nt  = blockIdx.x >> 4;
    const int tid = threadIdx.x;
    const int colbase = nt * 64 + (nt < 8 ? 1 : 2);
    #pragma unroll
    for (int i = 0; i < 16; ++i) {
        int r = i * 4 + (tid >> 6);
        int c = tid & 63;
        L[r][c] = basis[(size_t)(kt * 64 + r) * BASIS_LD + colbase + c];
    }
    __syncthreads();
    #pragma unroll
    for (int i = 0; i < 16; ++i) {
        int n = i * 4 + (tid >> 6);
        int k = tid & 63;
        Bt[(size_t)(nt * 64 + n) * 1024 + kt * 64 + k] = f2bf(L[k][n]);
    }
}

__global__ __launch_bounds__(256, 2) void stft_gemm_fb(
    const float* __restrict__ x,
    const unsigned short* __restrict__ Bt,
    float* __restrict__ out)
{
    __shared__ unsigned short Al[BM * LDPAD];
    __shared__ unsigned short Bl[BN * LDPAD];
    const int bid = blockIdx.x;
    const int wg  = (bid & 7) * (GRID / 8) + (bid >> 3);
    const int ntile = wg & 7;
    const int mtile = (wg >> 3) % MTILES;
    const int batch = wg / (MTILES * NTILES);
    const int tid  = threadIdx.x;
    const int lane = tid & 63;
    const int wid  = tid >> 6;
    const int wr   = wid >> 1;
    const int wc   = wid & 1;
    const int t0 = mtile * BM;
    const int n0 = ntile * BN;
    const float* __restrict__ xb = x + (size_t)batch * NX;

    f32x4 acc[4][4];
    #pragma unroll
    for (int m = 0; m < 4; ++m)
        #pragma unroll
        for (int n = 0; n < 4; ++n)
            acc[m][n] = (f32x4)0.0f;

    for (int k0 = 0; k0 < KDIM; k0 += BK) {
        #pragma unroll
        for (int it = 0; it < 8; ++it) {
            int idx = it * 256 + tid;
            int row = idx >> 4;
            int c4  = idx & 15;
            int t   = t0 + row;
            float v0, v1, v2, v3;
            int j = t * 512 + k0 + c4 * 4 - 512;
            if (t <= 4096) {
                if (j >= 0 && j + 3 < NX) {
                    const float4 f = *(const float4*)(xb + j);
                    v0 = f.x; v1 = f.y; v2 = f.z; v3 = f.w;
                } else {
                    float vv[4];
                    #pragma unroll
                    for (int e = 0; e < 4; ++e) {
                        int jj = j + e;
                        if (jj < 0) jj = -jj;
                        else if (jj >= NX) jj = 2 * (NX - 1) - jj;
                        vv[e] = xb[jj];
                    }
                    v0 = vv[0]; v1 = vv[1]; v2 = vv[2]; v3 = vv[3];
                }
            } else {
                v0 = v1 = v2 = v3 = 0.0f;
            }
            union { unsigned short s[4]; uint32_t u[2]; } p;
            p.s[0] = f2bf(v0); p.s[1] = f2bf(v1);
            p.s[2] = f2bf(v2); p.s[3] = f2bf(v3);
            *(uint32_t*)(Al + row * LDPAD + c4 * 4)     = p.u[0];
            *(uint32_t*)(Al + row * LDPAD + c4 * 4 + 2) = p.u[1];
        }
        #pragma unroll
        for (int it = 0; it < 4; ++it) {
            int idx = it * 256 + tid;
            int n  = idx >> 3;
            int kc = idx & 7;
            uint4 v = *(const uint4*)(Bt + (size_t)(n0 + n) * 1024 + k0 + kc * 8);
            *(uint4*)(Bl + n * LDPAD + kc * 8) = v;
        }
        __syncthreads();
        #pragma unroll
        for (int ks = 0; ks < 2; ++ks) {
            bf16x8 af[4], bfr[4];
            #pragma unroll
            for (int m = 0; m < 4; ++m)
                af[m] = *(const bf16x8*)(Al + (wr * 64 + m * 16 + (lane & 15)) * LDPAD
                                            + ks * 32 + (lane >> 4) * 8);
            #pragma unroll
            for (int n = 0; n < 4; ++n)
                bfr[n] = *(const bf16x8*)(Bl + (wc * 64 + n * 16 + (lane & 15)) * LDPAD
                                             + ks * 32 + (lane >> 4) * 8);
            #pragma unroll
            for (int m = 0; m < 4; ++m)
                #pragma unroll
                for (int n = 0; n < 4; ++n)
                    acc[m][n] = __builtin_amdgcn_mfma_f32_16x16x32_bf16(
                        af[m], bfr[n], acc[m][n], 0, 0, 0);
        }
        __syncthreads();
    }
    const int colb = n0 + wc * 64 + (lane & 15);
    #pragma unroll
    for (int m = 0; m < 4; ++m) {
        const int trow0 = t0 + wr * 64 + m * 16 + ((lane >> 4) << 2);
        #pragma unroll
        for (int r = 0; r < 4; ++r) {
            const int t = trow0 + r;
            if (t > 4096) continue;
            const size_t rowbase = (size_t)batch * (NFRAMES * 512) + (size_t)t * 512;
            #pragma unroll
            for (int n = 0; n < 4; ++n) {
                const int gc = colb + n * 16;
                const size_t o = (size_t)(gc >> 9) * HALF_SZ + rowbase + (gc & 511);
                out[o] = acc[m][n][r];
            }
        }
    }
}

extern "C" void kernel_launch(void* const* d_in, const int* in_sizes, int n_in,
                              void* d_out, int out_size, void* d_ws, size_t ws_size,
                              hipStream_t stream) {
    const float* x     = (const float*)d_in[0];
    const float* basis = (const float*)d_in[1];
    float* out = (float*)d_out;

    if (ws_size >= WS_NEEDED) {
        unsigned short* xp    = (unsigned short*)d_ws;
        unsigned short* Bfrag = (unsigned short*)((char*)d_ws + BFRAG_OFF);
        convert_pad<<<(NBATCH * (PADLEN >> 2)) / 256, 256, 0, stream>>>(x, xp);
        basis_to_frag<<<512, 256, 0, stream>>>(basis, Bfrag);
        stft_gemm6<<<GRID, 256, 0, stream>>>(xp, Bfrag, out);
    } else {
        unsigned short* Bt = (unsigned short*)d_ws;
        basis_transpose_fb<<<256, 256, 0, stream>>>(basis, Bt);
        stft_gemm_fb<<<GRID, 256, 0, stream>>>(x, Bt, out);
    }
}